// Round 1
// baseline (650.100 us; speedup 1.0000x reference)
//
#include <hip/hip_runtime.h>

#define B_ 8
#define M_ 32
#define C_ 512
#define H_ 64
#define W_ 64
#define HW (H_*W_)
#define KC 32          // channels per k-chunk
#define NKT (C_/KC)    // 16 chunks
#define TW 4           // output tile width (w)
#define TH 2           // output tile height (h)
#define PW (TW+2)      // pm tile width  = 6
#define PH (TH+2)      // pm tile height = 4
#define NPM (PW*PH)    // 24

typedef __attribute__((ext_vector_type(8))) short short8;
typedef __attribute__((ext_vector_type(4))) float float4v;

static __device__ __forceinline__ short f2bf(float f) {
    unsigned u = __float_as_uint(f);
    unsigned r = (u + 0x7fffu + ((u >> 16) & 1u)) >> 16;   // round-nearest-even
    return (short)r;
}

// ---------------- Kernel 1: inverse L2 norms over channel axis ----------------
__global__ void norm_kernel(const float* __restrict__ Q, const float* __restrict__ Mb,
                            float* __restrict__ invq, float* __restrict__ invm) {
    int idx = blockIdx.x * 256 + threadIdx.x;
    const int total_q = B_ * HW;
    const int total   = total_q + M_ * HW;
    if (idx >= total) return;
    const float* src;
    float* dst;
    if (idx < total_q) {
        src = Q + (size_t)(idx / HW) * C_ * HW + (idx % HW);
        dst = invq + idx;
    } else {
        int j = idx - total_q;
        src = Mb + (size_t)(j / HW) * C_ * HW + (j % HW);
        dst = invm + j;
    }
    float ss = 0.f;
    #pragma unroll 4
    for (int c = 0; c < C_; ++c) {
        float v = src[(size_t)c * HW];
        ss = fmaf(v, v, ss);
    }
    *dst = 1.0f / fmaxf(sqrtf(ss), 1e-12f);
}

// ---------------- Kernel 2: fused windowed-cosine-sim / max / relu / mean ----------------
__global__ __launch_bounds__(512)
void gcm_kernel(const float* __restrict__ Q, const float* __restrict__ Mb,
                const float* __restrict__ invq, const float* __restrict__ invm,
                float* __restrict__ out) {
    // LDS tiles (bf16 stored as raw shorts)
    __shared__ __align__(16) short q_lds[TW*TH][16][KC];   // 8 KB  (rows 8..15 zero)
    __shared__ __align__(16) short m_lds[NPM][M_][KC];     // 48 KB

    const int tid = threadIdx.x;
    const int bx = blockIdx.x % (W_ / TW);
    const int by = blockIdx.x / (W_ / TW);
    const int w0 = bx * TW, h0 = by * TH;

    const int wid  = tid >> 6;
    const int lane = tid & 63;
    const int lw = wid & 3;          // wave -> output position in tile
    const int lh = wid >> 2;
    const int col = lane & 15;       // frag row/col index
    const int kg  = lane >> 4;       // k-group (0..3)
    const int mypos = lh * TW + lw;

    // zero whole q_lds once (rows 8..15 must be zero; 0..7 rewritten each chunk)
    for (int e = tid; e < TW*TH*16*KC; e += 512) ((short*)q_lds)[e] = 0;

    float4v acc[9][2];
    #pragma unroll
    for (int d = 0; d < 9; ++d)
        #pragma unroll
        for (int hf = 0; hf < 2; ++hf)
            acc[d][hf] = (float4v){0.f, 0.f, 0.f, 0.f};

    for (int kt = 0; kt < NKT; ++kt) {
        const int c0 = kt * KC;
        __syncthreads();
        // ---- stage q tile: 8 pos x 8 b x 32 k (normalized bf16) ----
        for (int e = tid; e < B_*KC*TH*TW; e += 512) {
            int pw_ = e & 3;  int r = e >> 2;
            int ph_ = r & 1;  r >>= 1;
            int ck  = r & 31; int b = r >> 5;
            int gh = h0 + ph_, gw = w0 + pw_;
            float v = Q[(((size_t)b * C_ + c0 + ck) * H_ + gh) * W_ + gw]
                    * invq[b * HW + gh * W_ + gw];
            q_lds[ph_*TW + pw_][b][ck] = f2bf(v);
        }
        // ---- stage m halo tile: 24 pm x 32 m x 32 k (normalized bf16, zero-pad OOB) ----
        for (int e = tid; e < NPM*M_*KC; e += 512) {
            int pw_ = e % PW; int r = e / PW;
            int ph_ = r % PH; r /= PH;
            int ck  = r & 31; int mi = r >> 5;
            int gh = h0 - 1 + ph_, gw = w0 - 1 + pw_;
            float v = 0.f;
            if ((unsigned)gh < (unsigned)H_ && (unsigned)gw < (unsigned)W_)
                v = Mb[(((size_t)mi * C_ + c0 + ck) * H_ + gh) * W_ + gw]
                  * invm[mi * HW + gh * W_ + gw];
            m_lds[ph_*PW + pw_][mi][ck] = f2bf(v);
        }
        __syncthreads();
        // ---- MFMA: D[b, m] += q_hat . m_hat for the wave's 9 shifts x 2 m-halves ----
        short8 aq = *(const short8*)&q_lds[mypos][col][kg * 8];
        #pragma unroll
        for (int dh = 0; dh < 3; ++dh)
            #pragma unroll
            for (int dw = 0; dw < 3; ++dw) {
                const int pm = (lh + dh) * PW + (lw + dw);
                #pragma unroll
                for (int hf = 0; hf < 2; ++hf) {
                    short8 bm = *(const short8*)&m_lds[pm][hf*16 + col][kg * 8];
                    acc[dh*3 + dw][hf] =
                        __builtin_amdgcn_mfma_f32_16x16x32_bf16(aq, bm, acc[dh*3 + dw][hf], 0, 0, 0);
                }
            }
    }

    // ---- epilogue: max over 9 shifts, relu, sum over 32 m, write 1 - mean ----
    float res[4];
    #pragma unroll
    for (int r = 0; r < 4; ++r) {
        float v0 = acc[0][0][r], v1 = acc[0][1][r];
        #pragma unroll
        for (int d = 1; d < 9; ++d) {
            v0 = fmaxf(v0, acc[d][0][r]);
            v1 = fmaxf(v1, acc[d][1][r]);
        }
        res[r] = fmaxf(v0, 0.f) + fmaxf(v1, 0.f);
    }
    #pragma unroll
    for (int mask = 1; mask < 16; mask <<= 1)
        #pragma unroll
        for (int r = 0; r < 4; ++r)
            res[r] += __shfl_xor(res[r], mask);

    if (col == 0 && kg < 2) {
        const int gh = h0 + lh, gw = w0 + lw;
        #pragma unroll
        for (int r = 0; r < 4; ++r) {
            int b = kg * 4 + r;   // D row = (lane>>4)*4 + r
            out[(size_t)b * HW + gh * W_ + gw] = 1.0f - res[r] * (1.0f / M_);
        }
    }
}

extern "C" void kernel_launch(void* const* d_in, const int* in_sizes, int n_in,
                              void* d_out, int out_size, void* d_ws, size_t ws_size,
                              hipStream_t stream) {
    const float* Q  = (const float*)d_in[0];   // (8, 512, 64, 64)
    const float* Mb = (const float*)d_in[1];   // (32, 512, 64, 64)
    float* out = (float*)d_out;                // (8, 1, 64, 64)

    float* invq = (float*)d_ws;                // 8*4096 floats
    float* invm = invq + B_ * HW;              // 32*4096 floats

    {
        int total = (B_ + M_) * HW;
        int blocks = (total + 255) / 256;
        norm_kernel<<<blocks, 256, 0, stream>>>(Q, Mb, invq, invm);
    }
    {
        dim3 grid((W_ / TW) * (H_ / TH));      // 16 * 32 = 512 blocks
        gcm_kernel<<<grid, 512, 0, stream>>>(Q, Mb, invq, invm, out);
    }
}

// Round 2
// 240.830 us; speedup vs baseline: 2.6994x; 2.6994x over previous
//
#include <hip/hip_runtime.h>

#define B_ 8
#define M_ 32
#define C_ 512
#define H_ 64
#define W_ 64
#define HW 4096
#define NKT 16
#define KC 32
// gcm tile
#define TW 4
#define TH 4
#define NPOS 16
#define PW 6
#define PH 6
#define NPM 36
// padded m grid
#define HP 66
#define WP 66

typedef __attribute__((ext_vector_type(8))) short short8;
typedef __attribute__((ext_vector_type(4))) float float4v;

static __device__ __forceinline__ short f2bf(float f) {
    unsigned u = __float_as_uint(f);
    unsigned r = (u + 0x7fffu + ((u >> 16) & 1u)) >> 16;   // RNE
    return (short)r;
}

static __device__ __forceinline__ void load_lds16(const short* g, short* l) {
    __builtin_amdgcn_global_load_lds((const __attribute__((address_space(1))) void*)g,
                                     (__attribute__((address_space(3))) void*)l, 16, 0, 0);
}

// ---------- zero the halo ring of mT ----------
__global__ void zero_ring(short* __restrict__ mT) {
    int j = blockIdx.x * 256 + threadIdx.x;
    if (j >= NKT * 260 * 128) return;          // 260 ring cells, 128 x 16B each
    int e  = j & 127;
    int r  = (j >> 7) % 260;
    int kt = j / (260 * 128);
    int pos2;
    if (r < 66)       pos2 = r;                       // top row
    else if (r < 132) pos2 = 65 * WP + (r - 66);      // bottom row
    else { int rr = r - 132; pos2 = (1 + (rr >> 1)) * WP + ((rr & 1) ? 65 : 0); }
    short8 z = (short8){0,0,0,0,0,0,0,0};
    *(short8*)(mT + ((size_t)kt * (HP * WP) + pos2) * (M_ * KC) + e * 8) = z;
}

// ---------- prep: fused norms + bf16 convert + relayout ----------
__global__ __launch_bounds__(512)
void prep_kernel(const float* __restrict__ Q, const float* __restrict__ Mb,
                 short* __restrict__ qT, short* __restrict__ mT,
                 float* __restrict__ invq, float* __restrict__ invm) {
    int img = blockIdx.x >> 6;          // 0..39
    int gh  = blockIdx.x & 63;
    int p   = threadIdx.x & 63;         // gw
    int s   = threadIdx.x >> 6;         // c-slice 0..7
    const float* src = (img < B_ ? Q + (size_t)img * C_ * HW
                                 : Mb + (size_t)(img - B_) * C_ * HW) + gh * W_ + p;
    int pos = gh * W_ + p;
    float ss = 0.f;
    #pragma unroll
    for (int half = 0; half < 2; ++half) {
        int kt = 2 * s + half;
        int c0 = kt * KC;
        short* dst;
        if (img < B_) dst = qT + (((size_t)kt * HW + pos) * B_ + img) * KC;
        else          dst = mT + (((size_t)kt * (HP * WP) + (gh + 1) * WP + (p + 1)) * M_ + (img - B_)) * KC;
        #pragma unroll
        for (int ck8 = 0; ck8 < 4; ++ck8) {
            short8 v8;
            #pragma unroll
            for (int jj = 0; jj < 8; ++jj) {
                float v = src[(size_t)(c0 + ck8 * 8 + jj) * HW];
                ss = fmaf(v, v, ss);
                v8[jj] = f2bf(v);
            }
            *(short8*)(dst + ck8 * 8) = v8;
        }
    }
    __shared__ float ssp[8][64];
    ssp[s][p] = ss;
    __syncthreads();
    if (threadIdx.x < 64) {
        float t = 0.f;
        #pragma unroll
        for (int i = 0; i < 8; ++i) t += ssp[i][threadIdx.x];
        float inv = 1.0f / fmaxf(sqrtf(t), 1e-12f);
        int pp = gh * W_ + threadIdx.x;
        if (img < B_) invq[img * HW + pp] = inv;
        else          invm[(img - B_) * HW + pp] = inv;
    }
}

// ---------- gcm: MFMA on raw bf16, post-scaled epilogue ----------
__global__ __launch_bounds__(1024)
void gcm_kernel(const short* __restrict__ qT, const short* __restrict__ mT,
                const float* __restrict__ invq, const float* __restrict__ invm,
                float* __restrict__ out) {
    __shared__ __align__(16) short m_lds[NPM * M_ * KC];   // 72 KB
    __shared__ __align__(16) short q_lds[NPOS * 16 * KC];  // 16 KB

    const int tid = threadIdx.x;
    const int bx = blockIdx.x & 15, by = blockIdx.x >> 4;
    const int w0 = bx * TW, h0 = by * TH;
    const int wid = tid >> 6, lane = tid & 63;
    const int lw = wid & 3, lh = wid >> 2;
    const int col = lane & 15, kg = lane >> 4;
    const int mypos = lh * TW + lw;
    const int gh = h0 + lh, gw = w0 + lw;

    // zero q_lds (rows 8..15 stay zero forever; rows 0..7 rewritten per chunk)
    {
        short8 z = (short8){0,0,0,0,0,0,0,0};
        *(short8*)&q_lds[tid * 8] = z;   // 1024 threads x 8 shorts = 8192
    }

    float4v acc[9][2];
    #pragma unroll
    for (int d = 0; d < 9; ++d)
        #pragma unroll
        for (int hf = 0; hf < 2; ++hf)
            acc[d][hf] = (float4v){0.f, 0.f, 0.f, 0.f};

    for (int kt = 0; kt < NKT; ++kt) {
        __syncthreads();   // LDS free to overwrite (also covers init on kt==0)
        // ---- stage q: 16 pos x 8 rows x 32 ck = 8 KB, linear ds_write_b128 ----
        if (tid < 512) {
            int chunk = tid & 3, b = (tid >> 2) & 7, pidx = tid >> 5;
            int qh = h0 + (pidx >> 2), qw = w0 + (pidx & 3);
            const short* src = qT + (((size_t)kt * HW + qh * W_ + qw) * B_ + b) * KC + chunk * 8;
            *(short8*)&q_lds[pidx * 512 + b * KC + chunk * 8] = *(const short8*)src;
        }
        // ---- stage m: 36 regions x 2048 B via global_load_lds (1 KB per wave-call) ----
        for (int j = wid; j < NPM * 2; j += 16) {
            int pm = j >> 1, half = j & 1;
            int ph = pm / PW, pw = pm % PW;
            size_t pos2 = (size_t)(h0 + ph) * WP + (w0 + pw);
            const short* gsrc = mT + ((size_t)kt * (HP * WP) + pos2) * (M_ * KC)
                              + half * 512 + (size_t)lane * 8;
            short* ldst = m_lds + pm * 1024 + half * 512;
            load_lds16(gsrc, ldst);
        }
        __syncthreads();   // compiler drains vmcnt+lgkmcnt here
        // ---- 18 MFMAs ----
        short8 aq = *(const short8*)&q_lds[mypos * 512 + col * KC + kg * 8];
        #pragma unroll
        for (int dh = 0; dh < 3; ++dh)
            #pragma unroll
            for (int dw = 0; dw < 3; ++dw) {
                const int pm = (lh + dh) * PW + (lw + dw);
                #pragma unroll
                for (int hf = 0; hf < 2; ++hf) {
                    short8 bm = *(const short8*)&m_lds[pm * 1024 + (hf * 16 + col) * KC + kg * 8];
                    acc[dh * 3 + dw][hf] =
                        __builtin_amdgcn_mfma_f32_16x16x32_bf16(aq, bm, acc[dh * 3 + dw][hf], 0, 0, 0);
                }
            }
    }

    // ---- epilogue: scale by invq*invm, max over 9, relu, sum over m ----
    float iq[4];
    #pragma unroll
    for (int r = 0; r < 4; ++r)
        iq[r] = invq[(((kg & 1) * 4 + r) & 7) * HW + gh * W_ + gw];
    float im[2][9];
    #pragma unroll
    for (int dh = 0; dh < 3; ++dh)
        #pragma unroll
        for (int dw = 0; dw < 3; ++dw) {
            int hh = min(63, max(0, gh + dh - 1));
            int ww = min(63, max(0, gw + dw - 1));
            #pragma unroll
            for (int hf = 0; hf < 2; ++hf)
                im[hf][dh * 3 + dw] = invm[(hf * 16 + col) * HW + hh * W_ + ww];
        }
    float res[4];
    #pragma unroll
    for (int r = 0; r < 4; ++r) {
        float v0 = -1e30f, v1 = -1e30f;
        #pragma unroll
        for (int d = 0; d < 9; ++d) {
            v0 = fmaxf(v0, acc[d][0][r] * im[0][d]);
            v1 = fmaxf(v1, acc[d][1][r] * im[1][d]);
        }
        res[r] = fmaxf(v0 * iq[r], 0.f) + fmaxf(v1 * iq[r], 0.f);
    }
    #pragma unroll
    for (int mask = 1; mask < 16; mask <<= 1)
        #pragma unroll
        for (int r = 0; r < 4; ++r)
            res[r] += __shfl_xor(res[r], mask);

    if (col == 0 && kg < 2) {
        #pragma unroll
        for (int r = 0; r < 4; ++r) {
            int b = kg * 4 + r;
            out[(size_t)b * HW + gh * W_ + gw] = 1.0f - res[r] * (1.0f / M_);
        }
    }
}

extern "C" void kernel_launch(void* const* d_in, const int* in_sizes, int n_in,
                              void* d_out, int out_size, void* d_ws, size_t ws_size,
                              hipStream_t stream) {
    const float* Q  = (const float*)d_in[0];
    const float* Mb = (const float*)d_in[1];
    float* out = (float*)d_out;

    const size_t MT_SHORTS = (size_t)NKT * HP * WP * M_ * KC;  // 71,368,704
    const size_t QT_SHORTS = (size_t)NKT * HW * B_ * KC;       // 16,777,216
    short* mT = (short*)d_ws;
    short* qT = mT + MT_SHORTS;
    float* invq = (float*)(qT + QT_SHORTS);
    float* invm = invq + B_ * HW;

    {
        int jobs = NKT * 260 * 128;
        zero_ring<<<(jobs + 255) / 256, 256, 0, stream>>>(mT);
    }
    prep_kernel<<<40 * 64, 512, 0, stream>>>(Q, Mb, qT, mT, invq, invm);
    gcm_kernel<<<256, 1024, 0, stream>>>(qT, mT, invq, invm, out);
}

// Round 4
// 164.914 us; speedup vs baseline: 3.9420x; 1.4603x over previous
//
#include <hip/hip_runtime.h>

#define B_ 8
#define M_ 32
#define C_ 512
#define H_ 64
#define W_ 64
#define HW 4096
#define NKT 16
#define KC 32
// gcm tile
#define TW 4
#define TH 4
#define NPOS 16
#define PW 6
#define PH 6
#define NPM 36
// padded m grid
#define HP 66
#define WP 66

typedef __attribute__((ext_vector_type(8))) short short8;
typedef __attribute__((ext_vector_type(4))) short short4v;
typedef __attribute__((ext_vector_type(4))) float float4v;

static __device__ __forceinline__ short f2bf(float f) {
    unsigned u = __float_as_uint(f);
    unsigned r = (u + 0x7fffu + ((u >> 16) & 1u)) >> 16;   // RNE
    return (short)r;
}

static __device__ __forceinline__ void load_lds16(const short* g, short* l) {
    __builtin_amdgcn_global_load_lds((const __attribute__((address_space(1))) void*)g,
                                     (__attribute__((address_space(3))) void*)l, 16, 0, 0);
}

// ---------- prep: fused norms + bf16 convert + relayout (q and m in one launch) ----------
// blocks 0..255   : q  (pair pr=blk>>6 of 4, row h=blk&63)
// blocks 256..1279: m  (pair pr of 16, row h)
__global__ __launch_bounds__(512)
void prep_kernel(const float* __restrict__ Q, const float* __restrict__ Mb,
                 short* __restrict__ qT, short* __restrict__ mT,
                 float* __restrict__ invq, float* __restrict__ invm) {
    __shared__ __align__(16) short lds[2 * KC * 64];   // 8 KB: [bi][ck][w-swizzled]

    const int tid = threadIdx.x;
    const bool isq = (blockIdx.x < 256);
    const int g = isq ? blockIdx.x : (blockIdx.x - 256);
    const int pr = g >> 6;
    const int h  = g & 63;
    const float* src = (isq ? Q : Mb) + (size_t)(pr * 2) * C_ * HW + h * W_;

    // read roles
    const int w4 = tid & 15;          // float4 index along w
    const int cc = (tid >> 4) & 31;   // channel within chunk
    // store roles
    const int sck0 = (tid & 3) * 8;
    const int sbi  = (tid >> 2) & 1;
    const int sw   = tid >> 3;

    float4v ssq0 = (float4v){0.f,0.f,0.f,0.f};
    float4v ssq1 = (float4v){0.f,0.f,0.f,0.f};

    for (int kt = 0; kt < NKT; ++kt) {
        // ---- read + convert + stage (both images of the pair) ----
        #pragma unroll
        for (int it = 0; it < 2; ++it) {
            const float4v v = *(const float4v*)(src + (size_t)it * C_ * HW
                                                + (size_t)(kt * KC + cc) * HW + w4 * 4);
            if (it == 0) ssq0 += v * v; else ssq1 += v * v;
            short4v b;
            #pragma unroll
            for (int j = 0; j < 4; ++j) b[j] = f2bf(v[j]);
            *(short4v*)&lds[it * 2048 + cc * 64 + ((w4 * 4) ^ ((cc & 15) << 2))] = b;
        }
        __syncthreads();
        // ---- gather transposed + coalesced 128B-segment store ----
        short8 o;
        #pragma unroll
        for (int k = 0; k < 8; ++k) {
            int ck = sck0 + k;
            o[k] = lds[sbi * 2048 + ck * 64 + (sw ^ ((ck & 15) << 2))];
        }
        if (isq) {
            short* dst = qT + (((size_t)kt * HW + h * W_ + sw) * B_ + (pr * 2 + sbi)) * KC + sck0;
            *(short8*)dst = o;
        } else {
            short* dst = mT + (((size_t)kt * (HP * WP) + (size_t)(h + 1) * WP + (sw + 1)) * M_
                               + (pr * 2 + sbi)) * KC + sck0;
            *(short8*)dst = o;
        }
        __syncthreads();
    }

    // ---- norms: reduce ssq over channels ----
    #pragma unroll
    for (int d = 16; d <= 32; d <<= 1) {
        #pragma unroll
        for (int j = 0; j < 4; ++j) {
            ssq0[j] += __shfl_xor(ssq0[j], d);
            ssq1[j] += __shfl_xor(ssq1[j], d);
        }
    }
    float* red = (float*)lds;   // 4 KB reuse
    if ((tid & 63) < 16) {
        int wv = tid >> 6, l = tid & 15;
        #pragma unroll
        for (int j = 0; j < 4; ++j) {
            red[((wv * 16 + l) * 2 + 0) * 4 + j] = ssq0[j];
            red[((wv * 16 + l) * 2 + 1) * 4 + j] = ssq1[j];
        }
    }
    __syncthreads();
    if (tid < 128) {
        int bi = tid >> 6, w = tid & 63;
        int w4_ = w >> 2, sub = w & 3;
        float t = 0.f;
        #pragma unroll
        for (int wv = 0; wv < 8; ++wv) t += red[((wv * 16 + w4_) * 2 + bi) * 4 + sub];
        float inv = 1.0f / fmaxf(sqrtf(t), 1e-12f);
        int img = pr * 2 + bi;
        (isq ? invq : invm)[img * HW + h * W_ + w] = inv;
    }

    // ---- m-blocks: zero the halo ring slice for this pair ----
    if (!isq) {
        short8 z = (short8){0,0,0,0,0,0,0,0};
        if (tid < 16) {                         // cols 0 and 65 of row h+1
            int cell = tid >> 3, e = tid & 7;
            size_t pos2 = (size_t)(h + 1) * WP + (cell ? 65 : 0);
            for (int kt = 0; kt < NKT; ++kt)
                *(short8*)(mT + ((size_t)kt * (HP * WP) + pos2) * (M_ * KC) + pr * 64 + e * 8) = z;
        }
        if (h == 0 || h == 63) {                // full rows 0 / 65
            int row = (h == 0) ? 0 : 65;
            for (int j = tid; j < 66 * 8; j += 512) {
                int cell = j >> 3, e = j & 7;
                for (int kt = 0; kt < NKT; ++kt)
                    *(short8*)(mT + ((size_t)kt * (HP * WP) + (size_t)row * WP + cell) * (M_ * KC)
                               + pr * 64 + e * 8) = z;
            }
        }
    }
}

// ---------- gcm: MFMA on raw bf16, post-scaled epilogue (unchanged from R2) ----------
__global__ __launch_bounds__(1024)
void gcm_kernel(const short* __restrict__ qT, const short* __restrict__ mT,
                const float* __restrict__ invq, const float* __restrict__ invm,
                float* __restrict__ out) {
    __shared__ __align__(16) short m_lds[NPM * M_ * KC];   // 72 KB
    __shared__ __align__(16) short q_lds[NPOS * 16 * KC];  // 16 KB

    const int tid = threadIdx.x;
    const int bx = blockIdx.x & 15, by = blockIdx.x >> 4;
    const int w0 = bx * TW, h0 = by * TH;
    const int wid = tid >> 6, lane = tid & 63;
    const int lw = wid & 3, lh = wid >> 2;
    const int col = lane & 15, kg = lane >> 4;
    const int mypos = lh * TW + lw;
    const int gh = h0 + lh, gw = w0 + lw;

    {
        short8 z = (short8){0,0,0,0,0,0,0,0};
        *(short8*)&q_lds[tid * 8] = z;
    }

    float4v acc[9][2];
    #pragma unroll
    for (int d = 0; d < 9; ++d)
        #pragma unroll
        for (int hf = 0; hf < 2; ++hf)
            acc[d][hf] = (float4v){0.f, 0.f, 0.f, 0.f};

    for (int kt = 0; kt < NKT; ++kt) {
        __syncthreads();
        if (tid < 512) {
            int chunk = tid & 3, b = (tid >> 2) & 7, pidx = tid >> 5;
            int qh = h0 + (pidx >> 2), qw = w0 + (pidx & 3);
            const short* src = qT + (((size_t)kt * HW + qh * W_ + qw) * B_ + b) * KC + chunk * 8;
            *(short8*)&q_lds[pidx * 512 + b * KC + chunk * 8] = *(const short8*)src;
        }
        for (int j = wid; j < NPM * 2; j += 16) {
            int pm = j >> 1, half = j & 1;
            int ph = pm / PW, pw = pm % PW;
            size_t pos2 = (size_t)(h0 + ph) * WP + (w0 + pw);
            const short* gsrc = mT + ((size_t)kt * (HP * WP) + pos2) * (M_ * KC)
                              + half * 512 + (size_t)lane * 8;
            short* ldst = m_lds + pm * 1024 + half * 512;
            load_lds16(gsrc, ldst);
        }
        __syncthreads();
        short8 aq = *(const short8*)&q_lds[mypos * 512 + col * KC + kg * 8];
        #pragma unroll
        for (int dh = 0; dh < 3; ++dh)
            #pragma unroll
            for (int dw = 0; dw < 3; ++dw) {
                const int pm = (lh + dh) * PW + (lw + dw);
                #pragma unroll
                for (int hf = 0; hf < 2; ++hf) {
                    short8 bm = *(const short8*)&m_lds[pm * 1024 + (hf * 16 + col) * KC + kg * 8];
                    acc[dh * 3 + dw][hf] =
                        __builtin_amdgcn_mfma_f32_16x16x32_bf16(aq, bm, acc[dh * 3 + dw][hf], 0, 0, 0);
                }
            }
    }

    float iq[4];
    #pragma unroll
    for (int r = 0; r < 4; ++r)
        iq[r] = invq[(((kg & 1) * 4 + r) & 7) * HW + gh * W_ + gw];
    float im[2][9];
    #pragma unroll
    for (int dh = 0; dh < 3; ++dh)
        #pragma unroll
        for (int dw = 0; dw < 3; ++dw) {
            int hh = min(63, max(0, gh + dh - 1));
            int ww = min(63, max(0, gw + dw - 1));
            #pragma unroll
            for (int hf = 0; hf < 2; ++hf)
                im[hf][dh * 3 + dw] = invm[(hf * 16 + col) * HW + hh * W_ + ww];
        }
    float res[4];
    #pragma unroll
    for (int r = 0; r < 4; ++r) {
        float v0 = -1e30f, v1 = -1e30f;
        #pragma unroll
        for (int d = 0; d < 9; ++d) {
            v0 = fmaxf(v0, acc[d][0][r] * im[0][d]);
            v1 = fmaxf(v1, acc[d][1][r] * im[1][d]);
        }
        res[r] = fmaxf(v0 * iq[r], 0.f) + fmaxf(v1 * iq[r], 0.f);
    }
    #pragma unroll
    for (int mask = 1; mask < 16; mask <<= 1)
        #pragma unroll
        for (int r = 0; r < 4; ++r)
            res[r] += __shfl_xor(res[r], mask);

    if (col == 0 && kg < 2) {
        #pragma unroll
        for (int r = 0; r < 4; ++r) {
            int b = kg * 4 + r;
            out[(size_t)b * HW + gh * W_ + gw] = 1.0f - res[r] * (1.0f / M_);
        }
    }
}

extern "C" void kernel_launch(void* const* d_in, const int* in_sizes, int n_in,
                              void* d_out, int out_size, void* d_ws, size_t ws_size,
                              hipStream_t stream) {
    const float* Q  = (const float*)d_in[0];
    const float* Mb = (const float*)d_in[1];
    float* out = (float*)d_out;

    const size_t MT_SHORTS = (size_t)NKT * HP * WP * M_ * KC;  // 71,368,704
    const size_t QT_SHORTS = (size_t)NKT * HW * B_ * KC;       // 16,777,216
    short* mT = (short*)d_ws;
    short* qT = mT + MT_SHORTS;
    float* invq = (float*)(qT + QT_SHORTS);
    float* invm = invq + B_ * HW;

    prep_kernel<<<1280, 512, 0, stream>>>(Q, Mb, qT, mT, invq, invm);
    gcm_kernel<<<256, 1024, 0, stream>>>(qT, mT, invq, invm, out);
}